// Round 3
// baseline (478.250 us; speedup 1.0000x reference)
//
#include <hip/hip_runtime.h>

#define IN_F 4096
#define OUT_F 4096
#define M_ROWS 8192
#define GK 4096

typedef float  floatx4 __attribute__((ext_vector_type(4)));
typedef short  shortx8 __attribute__((ext_vector_type(8)));

__device__ __forceinline__ unsigned short f2bf(float f) {
    unsigned int u = __float_as_uint(f);
    u = (u + 0x7FFFu + ((u >> 16) & 1u)) >> 16;
    return (unsigned short)u;
}

__device__ __forceinline__ float bf2f(unsigned short u) {
    return __uint_as_float((unsigned)u << 16);
}

__constant__ float NF4_TAB[16] = {
    -1.0f, -0.6961928009986877f, -0.5250730514526367f, -0.39491748809814453f,
    -0.28444138169288635f, -0.18477343022823334f, -0.09105003625154495f, 0.0f,
    0.07958029955625534f, 0.16093020141124725f, 0.2461123913526535f, 0.33791524171829224f,
    0.44070982933044434f, 0.5626170039176941f, 0.7229568362236023f, 1.0f
};

__device__ __forceinline__ void gll16(const void* g, void* l) {
    __builtin_amdgcn_global_load_lds(
        (const __attribute__((address_space(1))) void*)g,
        (__attribute__((address_space(3))) void*)l, 16, 0, 0);
}

// ---------------------------------------------------------------------------
// prep: one launch for all three casts. (unchanged)
// ---------------------------------------------------------------------------
__global__ __launch_bounds__(256) void prep(
    const float* __restrict__ A, const float* __restrict__ Bm,
    const float* __restrict__ x,
    short* __restrict__ At, short* __restrict__ Bb, short* __restrict__ Xb)
{
    __shared__ float tile[64][65];
    const int b = blockIdx.x;
    const int t = threadIdx.x;

    if (b < 64) {
        const int ib = b * 64;
        const int r = t >> 2, c0 = (t & 3) * 16;
        #pragma unroll
        for (int k = 0; k < 4; ++k) {
            float4 v = *(const float4*)(A + (size_t)r * IN_F + ib + c0 + k * 4);
            tile[r][c0 + k * 4 + 0] = v.x;
            tile[r][c0 + k * 4 + 1] = v.y;
            tile[r][c0 + k * 4 + 2] = v.z;
            tile[r][c0 + k * 4 + 3] = v.w;
        }
        __syncthreads();
        const int i = t >> 2, r0 = (t & 3) * 16;
        union { unsigned short u[8]; int4 v; } p0, p1;
        #pragma unroll
        for (int k = 0; k < 8; ++k) p0.u[k] = f2bf(tile[r0 + k][i]);
        #pragma unroll
        for (int k = 0; k < 8; ++k) p1.u[k] = f2bf(tile[r0 + 8 + k][i]);
        *(int4*)(At + (size_t)(ib + i) * 64 + r0)     = p0.v;
        *(int4*)(At + (size_t)(ib + i) * 64 + r0 + 8) = p1.v;
    } else if (b < 192) {
        const size_t i = ((size_t)(b - 64) * 256 + t) * 8;
        float4 a = *(const float4*)(Bm + i);
        float4 c = *(const float4*)(Bm + i + 4);
        union { unsigned short u[8]; int4 v; } p;
        p.u[0] = f2bf(a.x); p.u[1] = f2bf(a.y); p.u[2] = f2bf(a.z); p.u[3] = f2bf(a.w);
        p.u[4] = f2bf(c.x); p.u[5] = f2bf(c.y); p.u[6] = f2bf(c.z); p.u[7] = f2bf(c.w);
        *(int4*)(Bb + i) = p.v;
    } else {
        const size_t i = ((size_t)(b - 192) * 256 + t) * 8;
        float4 a = *(const float4*)(x + i);
        float4 c = *(const float4*)(x + i + 4);
        union { unsigned short u[8]; int4 v; } p;
        p.u[0] = f2bf(a.x); p.u[1] = f2bf(a.y); p.u[2] = f2bf(a.z); p.u[3] = f2bf(a.w);
        p.u[4] = f2bf(c.x); p.u[5] = f2bf(c.y); p.u[6] = f2bf(c.z); p.u[7] = f2bf(c.w);
        *(int4*)(Xb + i) = p.v;
    }
}

// ---------------------------------------------------------------------------
// lora_weff: (unchanged)
// ---------------------------------------------------------------------------
#define BM 128
#define BN 128

__global__ __launch_bounds__(256) void lora_weff(
    const short* __restrict__ Bb,      // OUT_F x 64 bf16
    const short* __restrict__ At,      // IN_F x 64 bf16
    const int*   __restrict__ qw,      // int32 per byte, 2 nibbles
    const float* __restrict__ absmax,
    short*       __restrict__ W)       // OUT_F x IN_F bf16
{
    __shared__ union SMem {
        struct { short As[BM * 32]; short Bs[BN * 32]; } mm;
        short Wt[128 * 136];           // [col][row], pad 136 vs 128
    } sm;
    __shared__ float nf4s[16];

    const int tid  = threadIdx.x;
    const int lane = tid & 63;
    const int wave = tid >> 6;
    const int bn = blockIdx.x * BN;   // i dim
    const int bm = blockIdx.y * BM;   // o dim

    if (tid < 16) nf4s[tid] = NF4_TAB[tid];

    const int r_o = tid >> 1;          // local output row 0..127
    const int h   = tid & 1;           // which 64-col half
    const int go  = bm + r_o;          // global o
    const int* qbase = qw + (size_t)go * 2048 + (bn >> 1) + h * 32;
    int4 q4[8];
    #pragma unroll
    for (int k = 0; k < 8; ++k) q4[k] = *(const int4*)(qbase + 4 * k);
    const float am = absmax[(size_t)go * 64 + (bn >> 6) + h];

    const int ar = tid >> 2;
    const int ac = ((tid & 3) ^ ((ar >> 1) & 3)) * 8;
    const short* gA0 = Bb + (size_t)(bm + ar) * 64 + ac;
    const short* gA1 = gA0 + (size_t)64 * 64;
    const short* gB0 = At + (size_t)(bn + ar) * 64 + ac;
    const short* gB1 = gB0 + (size_t)64 * 64;
    short* lA0 = sm.mm.As + tid * 8;
    short* lA1 = sm.mm.As + 2048 + tid * 8;
    short* lB0 = sm.mm.Bs + tid * 8;
    short* lB1 = sm.mm.Bs + 2048 + tid * 8;

    const int wm = (wave >> 1) * 64;
    const int wn = (wave & 1) * 64;
    const int fr = lane & 15;
    const int qd = lane >> 4;
    const int fk_sw = (((lane >> 4) ^ ((fr >> 1) & 3))) * 8;

    floatx4 zero = {0.f, 0.f, 0.f, 0.f};
    floatx4 acc[4][4];
    #pragma unroll
    for (int i = 0; i < 4; ++i)
        #pragma unroll
        for (int j = 0; j < 4; ++j) acc[i][j] = zero;

    #pragma unroll
    for (int kt = 0; kt < 2; ++kt) {
        gll16(gA0, lA0);
        gll16(gA1, lA1);
        gll16(gB0, lB0);
        gll16(gB1, lB1);
        gA0 += 32; gA1 += 32; gB0 += 32; gB1 += 32;
        __syncthreads();

        shortx8 af[4], bfr[4];
        #pragma unroll
        for (int i = 0; i < 4; ++i) {
            af[i]  = *(const shortx8*)&sm.mm.As[(wm + i * 16 + fr) * 32 + fk_sw];
            bfr[i] = *(const shortx8*)&sm.mm.Bs[(wn + i * 16 + fr) * 32 + fk_sw];
        }
        #pragma unroll
        for (int i = 0; i < 4; ++i)
            #pragma unroll
            for (int j = 0; j < 4; ++j)
                acc[i][j] = __builtin_amdgcn_mfma_f32_16x16x32_bf16(
                    af[i], bfr[j], acc[i][j], 0, 0, 0);
        __syncthreads();
    }

    #pragma unroll
    for (int i = 0; i < 4; ++i) {
        const int r0 = wm + i * 16 + qd * 4;
        #pragma unroll
        for (int j = 0; j < 4; ++j) {
            const int c = wn + j * 16 + fr;
            union { unsigned short u[4]; uint2 v; } p;
            p.u[0] = f2bf(acc[i][j][0]);
            p.u[1] = f2bf(acc[i][j][1]);
            p.u[2] = f2bf(acc[i][j][2]);
            p.u[3] = f2bf(acc[i][j][3]);
            *(uint2*)&sm.Wt[c * 136 + r0] = p.v;
        }
    }
    __syncthreads();

    short* out = W + (size_t)go * IN_F + bn + h * 64;
    #pragma unroll
    for (int k = 0; k < 8; ++k) {
        const int qs[4] = { q4[k].x, q4[k].y, q4[k].z, q4[k].w };
        union { unsigned short u[8]; int4 v; } p;
        #pragma unroll
        for (int d = 0; d < 4; ++d) {
            const int q = qs[d];
            const int c = h * 64 + k * 8 + d * 2;
            const float l0 = bf2f((unsigned short)sm.Wt[c * 136 + r_o]);
            const float l1 = bf2f((unsigned short)sm.Wt[(c + 1) * 136 + r_o]);
            p.u[2 * d]     = f2bf(fmaf(nf4s[q & 15],        am, l0));
            p.u[2 * d + 1] = f2bf(fmaf(nf4s[(q >> 4) & 15], am, l1));
        }
        *(int4*)(out + k * 8) = p.v;
    }
}

// ---------------------------------------------------------------------------
// gemm_bt2: C[M][N] = Xb[M][K] * Wb[N][K]^T
// 256x256 tile, BK=64, 512 threads (8 waves: 2M x 4N, 128x64 C each).
// ROUND-3 CHANGE: ONE barrier per window (4/K-tile, was 8). Window =
// [reads issue | stage issue] -> lgkmcnt(0) -> setprio MFMA -> s_barrier.
// Wave skew inside a window overlaps LDS-pipe (other waves' reads) with
// MFMA-pipe (this wave's quadrant) — the two ~2000-cyc/K-tile pipe loads
// no longer strictly alternate.
// Safety: per-wave lgkmcnt(0) precedes each wave's barrier arrival, so
// SBAR(W) ==> all reads of windows <= W are serviced. Every stage in
// window W overwrites a region last READ in window <= W-1 (P1->nxt.A1:
// last read t-1.P3; P3->cur.B: last read t.P2; P4->cur.A-lo: last read
// t.P1). Boundary vmcnt(6)+SBAR at P4 end (unchanged, verified round 2)
// guarantees T(t+1) fully landed before t+1.P1's reads.
// ---------------------------------------------------------------------------
#define BM2 256
#define BN2 256
#define BK2 64
#define NT2 (GK / BK2)   // 64

#define MFMA16(a, b, c) __builtin_amdgcn_mfma_f32_16x16x32_bf16((a), (b), (c), 0, 0, 0)
#define SBAR()  __builtin_amdgcn_s_barrier()
#define SFEN()  __builtin_amdgcn_sched_barrier(0)

__global__ __launch_bounds__(512, 2) void gemm_bt2(
    const short* __restrict__ Xb,   // M x K bf16
    const short* __restrict__ Wb,   // N x K bf16
    float*       __restrict__ C)    // M x N fp32
{
    // [buf:2][mat:2 (A,B)][half:2][row:128][k:64] bf16 = 128 KiB
    __shared__ short lds[2 * 32768];

    const int tid  = threadIdx.x;
    const int lane = tid & 63;
    const int wave = tid >> 6;
    const int bn = blockIdx.x * BN2;
    const int bm = blockIdx.y * BM2;

    const int wm = (wave >> 2) * 128;       // 0 or 128 (A half)
    const int wn = (wave & 3) * 64;         // 0,64,128,192
    const int fr = lane & 15;
    const int qd = lane >> 4;               // 0..3
    const int rsw = fr & 7;
    const int kof[2] = { ((0 * 4 + qd) ^ rsw) << 3, ((1 * 4 + qd) ^ rsw) << 3 };

    // staging: LDS dest linear in tid (gll16 requirement); global k-chunk
    // pre-swizzled: chunk = (tid&7) ^ (row&7).
    const int srow = tid >> 3;                       // 0..63
    const int gch  = (tid & 7) ^ (srow & 7);
    const short* pA = Xb + (size_t)(bm + srow) * GK + gch * 8;
    const short* pB = Wb + (size_t)(bn + srow) * GK + gch * 8;

    auto STAGE = [&](const short* P, int matOff, int h, int t, int buf) {
        short* d = lds + buf * 32768 + matOff + h * 8192 + tid * 8;
        const short* s = P + (size_t)(h * 128) * GK + (size_t)t * BK2;
        gll16(s, d);
        gll16(s + (size_t)64 * GK, d + 4096);
    };

    floatx4 zero = {0.f, 0.f, 0.f, 0.f};
    floatx4 acc[8][4];
    #pragma unroll
    for (int i = 0; i < 8; ++i)
        #pragma unroll
        for (int j = 0; j < 4; ++j) acc[i][j] = zero;

    // ---- prologue: T0 (4 half-tiles, buf0) + T1.{A0,B0,B1} (buf1) ----
    STAGE(pA, 0,     0, 0, 0);
    STAGE(pA, 0,     1, 0, 0);
    STAGE(pB, 16384, 0, 0, 0);
    STAGE(pB, 16384, 1, 0, 0);
    STAGE(pA, 0,     0, 1, 1);
    STAGE(pB, 16384, 0, 1, 1);
    STAGE(pB, 16384, 1, 1, 1);
    asm volatile("s_waitcnt vmcnt(6)" ::: "memory");   // T0 landed; T1 3 ht in flight
    SBAR();
    SFEN();

    for (int t = 0; t < NT2; ++t) {
        const int cur = t & 1;
        const short* Ah = lds + cur * 32768 + (wm >> 7) * 8192;
        const short* Bh = lds + cur * 32768 + 16384 + (wn >> 7) * 8192;
        const int bs = wn & 64;            // wave's strip base within B half

        shortx8 af[4][2], bf[4][2];

        // ---------------- P1: [rd A-lo(8)+B-lo(4) | stage T(t+1).A1] ->
        //                  lgkm -> MFMA Q(0,0) -> SBAR ----
        #pragma unroll
        for (int i = 0; i < 4; ++i) {
            af[i][0] = *(const shortx8*)(Ah + (i * 16 + fr) * 64 + kof[0]);
            af[i][1] = *(const shortx8*)(Ah + (i * 16 + fr) * 64 + kof[1]);
        }
        #pragma unroll
        for (int j = 0; j < 2; ++j) {
            bf[j][0] = *(const shortx8*)(Bh + (bs + j * 16 + fr) * 64 + kof[0]);
            bf[j][1] = *(const shortx8*)(Bh + (bs + j * 16 + fr) * 64 + kof[1]);
        }
        if (t + 1 < NT2) STAGE(pA, 0, 1, t + 1, cur ^ 1);
        SFEN();
        asm volatile("s_waitcnt lgkmcnt(0)" ::: "memory");
        SFEN();
        __builtin_amdgcn_s_setprio(1);
        #pragma unroll
        for (int i = 0; i < 4; ++i)
            #pragma unroll
            for (int j = 0; j < 2; ++j) {
                acc[i][j] = MFMA16(af[i][0], bf[j][0], acc[i][j]);
                acc[i][j] = MFMA16(af[i][1], bf[j][1], acc[i][j]);
            }
        __builtin_amdgcn_s_setprio(0);
        SFEN();
        SBAR();
        SFEN();

        // ---------------- P2: [rd B-hi(4)] -> lgkm -> MFMA Q(0,1) -> SBAR ----
        #pragma unroll
        for (int j = 0; j < 2; ++j) {
            bf[2 + j][0] = *(const shortx8*)(Bh + (bs + (2 + j) * 16 + fr) * 64 + kof[0]);
            bf[2 + j][1] = *(const shortx8*)(Bh + (bs + (2 + j) * 16 + fr) * 64 + kof[1]);
        }
        SFEN();
        asm volatile("s_waitcnt lgkmcnt(0)" ::: "memory");
        SFEN();
        __builtin_amdgcn_s_setprio(1);
        #pragma unroll
        for (int i = 0; i < 4; ++i)
            #pragma unroll
            for (int j = 2; j < 4; ++j) {
                acc[i][j] = MFMA16(af[i][0], bf[j][0], acc[i][j]);
                acc[i][j] = MFMA16(af[i][1], bf[j][1], acc[i][j]);
            }
        __builtin_amdgcn_s_setprio(0);
        SFEN();
        SBAR();
        SFEN();

        // ---------------- P3: [rd A-hi(8, reuse af) | stage T(t+2).B0,B1] ->
        //                  lgkm -> MFMA Q(1,1) -> SBAR ----
        #pragma unroll
        for (int i = 0; i < 4; ++i) {
            af[i][0] = *(const shortx8*)(Ah + (64 + i * 16 + fr) * 64 + kof[0]);
            af[i][1] = *(const shortx8*)(Ah + (64 + i * 16 + fr) * 64 + kof[1]);
        }
        if (t + 2 < NT2) {
            STAGE(pB, 16384, 0, t + 2, cur);
            STAGE(pB, 16384, 1, t + 2, cur);
        }
        SFEN();
        asm volatile("s_waitcnt lgkmcnt(0)" ::: "memory");
        SFEN();
        __builtin_amdgcn_s_setprio(1);
        #pragma unroll
        for (int i = 0; i < 4; ++i)
            #pragma unroll
            for (int j = 2; j < 4; ++j) {
                acc[4 + i][j] = MFMA16(af[i][0], bf[j][0], acc[4 + i][j]);
                acc[4 + i][j] = MFMA16(af[i][1], bf[j][1], acc[4 + i][j]);
            }
        __builtin_amdgcn_s_setprio(0);
        SFEN();
        SBAR();
        SFEN();

        // ---------------- P4: [stage T(t+2).A0] -> MFMA Q(1,0) ->
        //                  vmcnt(6) -> SBAR ----
        if (t + 2 < NT2) STAGE(pA, 0, 0, t + 2, cur);
        SFEN();
        __builtin_amdgcn_s_setprio(1);
        #pragma unroll
        for (int i = 0; i < 4; ++i)
            #pragma unroll
            for (int j = 0; j < 2; ++j) {
                acc[4 + i][j] = MFMA16(af[i][0], bf[j][0], acc[4 + i][j]);
                acc[4 + i][j] = MFMA16(af[i][1], bf[j][1], acc[4 + i][j]);
            }
        __builtin_amdgcn_s_setprio(0);
        SFEN();
        if (t < NT2 - 2) {
            asm volatile("s_waitcnt vmcnt(6)" ::: "memory");   // T(t+1) landed
        } else if (t == NT2 - 2) {
            asm volatile("s_waitcnt vmcnt(0)" ::: "memory");   // last tile landed
        }
        SBAR();
        SFEN();
    }

    // epilogue: C/D layout col=lane&15, row=(lane>>4)*4+reg
    const int row0 = bm + wm + qd * 4;
    const int col0 = bn + wn + fr;
    #pragma unroll
    for (int i = 0; i < 8; ++i)
        #pragma unroll
        for (int j = 0; j < 4; ++j) {
            float* cp = C + (size_t)(row0 + i * 16) * OUT_F + col0 + j * 16;
            #pragma unroll
            for (int rr = 0; rr < 4; ++rr)
                cp[(size_t)rr * OUT_F] = acc[i][j][rr];
        }
}

// ---------------------------------------------------------------------------
extern "C" void kernel_launch(void* const* d_in, const int* in_sizes, int n_in,
                              void* d_out, int out_size, void* d_ws, size_t ws_size,
                              hipStream_t stream) {
    const float* x  = (const float*)d_in[0];
    const int*   qw = (const int*)d_in[1];
    const float* am = (const float*)d_in[2];
    const float* lA = (const float*)d_in[3];
    const float* lB = (const float*)d_in[4];
    float* out = (float*)d_out;

    short* Weff = (short*)d_ws;                                     // 32 MiB
    short* Xb   = (short*)((char*)d_ws + (size_t)OUT_F * IN_F * 2); // 64 MiB
    short* At   = (short*)((char*)d_ws + (size_t)(OUT_F * IN_F + M_ROWS * IN_F) * 2);
    short* Bb   = At + (size_t)IN_F * 64;   // At/Bb: 2 x 512 KiB past Xb

    prep<<<192 + (M_ROWS * IN_F) / 2048, 256, 0, stream>>>(lA, lB, x, At, Bb, Xb);
    lora_weff<<<dim3(IN_F / 128, OUT_F / 128), 256, 0, stream>>>(Bb, At, qw, am, Weff);
    gemm_bt2<<<dim3(OUT_F / BN2, M_ROWS / BM2), 512, 0, stream>>>(Xb, Weff, out);
}

// Round 4
// 466.450 us; speedup vs baseline: 1.0253x; 1.0253x over previous
//
#include <hip/hip_runtime.h>

#define IN_F 4096
#define OUT_F 4096
#define M_ROWS 8192
#define GK 4096

typedef float  floatx4 __attribute__((ext_vector_type(4)));
typedef short  shortx8 __attribute__((ext_vector_type(8)));

__device__ __forceinline__ unsigned short f2bf(float f) {
    unsigned int u = __float_as_uint(f);
    u = (u + 0x7FFFu + ((u >> 16) & 1u)) >> 16;
    return (unsigned short)u;
}

__device__ __forceinline__ float bf2f(unsigned short u) {
    return __uint_as_float((unsigned)u << 16);
}

__constant__ float NF4_TAB[16] = {
    -1.0f, -0.6961928009986877f, -0.5250730514526367f, -0.39491748809814453f,
    -0.28444138169288635f, -0.18477343022823334f, -0.09105003625154495f, 0.0f,
    0.07958029955625534f, 0.16093020141124725f, 0.2461123913526535f, 0.33791524171829224f,
    0.44070982933044434f, 0.5626170039176941f, 0.7229568362236023f, 1.0f
};

__device__ __forceinline__ void gll16(const void* g, void* l) {
    __builtin_amdgcn_global_load_lds(
        (const __attribute__((address_space(1))) void*)g,
        (__attribute__((address_space(3))) void*)l, 16, 0, 0);
}

// ---------------------------------------------------------------------------
// prep: lora_A transpose-cast + lora_B cast only (x-cast moved into
// lora_weff's grid so it overlaps the weight-dequant compute).
//   blocks [0,64)   : lora_A (64 x IN_F fp32) -> At (IN_F x 64 bf16)
//   blocks [64,192) : lora_B (OUT_F x 64 fp32) -> Bb bf16
// ---------------------------------------------------------------------------
__global__ __launch_bounds__(256) void prep(
    const float* __restrict__ A, const float* __restrict__ Bm,
    short* __restrict__ At, short* __restrict__ Bb)
{
    __shared__ float tile[64][65];
    const int b = blockIdx.x;
    const int t = threadIdx.x;

    if (b < 64) {
        const int ib = b * 64;
        const int r = t >> 2, c0 = (t & 3) * 16;
        #pragma unroll
        for (int k = 0; k < 4; ++k) {
            float4 v = *(const float4*)(A + (size_t)r * IN_F + ib + c0 + k * 4);
            tile[r][c0 + k * 4 + 0] = v.x;
            tile[r][c0 + k * 4 + 1] = v.y;
            tile[r][c0 + k * 4 + 2] = v.z;
            tile[r][c0 + k * 4 + 3] = v.w;
        }
        __syncthreads();
        const int i = t >> 2, r0 = (t & 3) * 16;
        union { unsigned short u[8]; int4 v; } p0, p1;
        #pragma unroll
        for (int k = 0; k < 8; ++k) p0.u[k] = f2bf(tile[r0 + k][i]);
        #pragma unroll
        for (int k = 0; k < 8; ++k) p1.u[k] = f2bf(tile[r0 + 8 + k][i]);
        *(int4*)(At + (size_t)(ib + i) * 64 + r0)     = p0.v;
        *(int4*)(At + (size_t)(ib + i) * 64 + r0 + 8) = p1.v;
    } else {
        const size_t i = ((size_t)(b - 64) * 256 + t) * 8;
        float4 a = *(const float4*)(Bm + i);
        float4 c = *(const float4*)(Bm + i + 4);
        union { unsigned short u[8]; int4 v; } p;
        p.u[0] = f2bf(a.x); p.u[1] = f2bf(a.y); p.u[2] = f2bf(a.z); p.u[3] = f2bf(a.w);
        p.u[4] = f2bf(c.x); p.u[5] = f2bf(c.y); p.u[6] = f2bf(c.z); p.u[7] = f2bf(c.w);
        *(int4*)(Bb + i) = p.v;
    }
}

// ---------------------------------------------------------------------------
// lora_weff (+fused x-cast): blocks [0,1024) compute Weff tiles (unchanged
// math); blocks [1024, 1024+16384) stream-cast x fp32 -> Xb bf16, filling
// the CUs while weight blocks run / retire.
// ---------------------------------------------------------------------------
#define BM 128
#define BN 128

__global__ __launch_bounds__(256) void lora_weff(
    const short* __restrict__ Bb,      // OUT_F x 64 bf16
    const short* __restrict__ At,      // IN_F x 64 bf16
    const int*   __restrict__ qw,      // int32 per byte, 2 nibbles
    const float* __restrict__ absmax,
    short*       __restrict__ W,       // OUT_F x IN_F bf16
    const float* __restrict__ xin,
    short*       __restrict__ Xb)
{
    const int b = blockIdx.x;
    if (b >= 1024) {
        // ---- fused x-cast ----
        const size_t i = ((size_t)(b - 1024) * 256 + threadIdx.x) * 8;
        float4 a = *(const float4*)(xin + i);
        float4 c = *(const float4*)(xin + i + 4);
        union { unsigned short u[8]; int4 v; } p;
        p.u[0] = f2bf(a.x); p.u[1] = f2bf(a.y); p.u[2] = f2bf(a.z); p.u[3] = f2bf(a.w);
        p.u[4] = f2bf(c.x); p.u[5] = f2bf(c.y); p.u[6] = f2bf(c.z); p.u[7] = f2bf(c.w);
        *(int4*)(Xb + i) = p.v;
        return;
    }

    __shared__ union SMem {
        struct { short As[BM * 32]; short Bs[BN * 32]; } mm;
        short Wt[128 * 136];           // [col][row], pad 136 vs 128
    } sm;
    __shared__ float nf4s[16];

    const int tid  = threadIdx.x;
    const int lane = tid & 63;
    const int wave = tid >> 6;
    const int bn = (b & 31) * BN;     // i dim
    const int bm = (b >> 5) * BM;     // o dim

    if (tid < 16) nf4s[tid] = NF4_TAB[tid];

    const int r_o = tid >> 1;          // local output row 0..127
    const int h   = tid & 1;           // which 64-col half
    const int go  = bm + r_o;          // global o
    const int* qbase = qw + (size_t)go * 2048 + (bn >> 1) + h * 32;
    int4 q4[8];
    #pragma unroll
    for (int k = 0; k < 8; ++k) q4[k] = *(const int4*)(qbase + 4 * k);
    const float am = absmax[(size_t)go * 64 + (bn >> 6) + h];

    const int ar = tid >> 2;
    const int ac = ((tid & 3) ^ ((ar >> 1) & 3)) * 8;
    const short* gA0 = Bb + (size_t)(bm + ar) * 64 + ac;
    const short* gA1 = gA0 + (size_t)64 * 64;
    const short* gB0 = At + (size_t)(bn + ar) * 64 + ac;
    const short* gB1 = gB0 + (size_t)64 * 64;
    short* lA0 = sm.mm.As + tid * 8;
    short* lA1 = sm.mm.As + 2048 + tid * 8;
    short* lB0 = sm.mm.Bs + tid * 8;
    short* lB1 = sm.mm.Bs + 2048 + tid * 8;

    const int wm = (wave >> 1) * 64;
    const int wn = (wave & 1) * 64;
    const int fr = lane & 15;
    const int qd = lane >> 4;
    const int fk_sw = (((lane >> 4) ^ ((fr >> 1) & 3))) * 8;

    floatx4 zero = {0.f, 0.f, 0.f, 0.f};
    floatx4 acc[4][4];
    #pragma unroll
    for (int i = 0; i < 4; ++i)
        #pragma unroll
        for (int j = 0; j < 4; ++j) acc[i][j] = zero;

    #pragma unroll
    for (int kt = 0; kt < 2; ++kt) {
        gll16(gA0, lA0);
        gll16(gA1, lA1);
        gll16(gB0, lB0);
        gll16(gB1, lB1);
        gA0 += 32; gA1 += 32; gB0 += 32; gB1 += 32;
        __syncthreads();

        shortx8 af[4], bfr[4];
        #pragma unroll
        for (int i = 0; i < 4; ++i) {
            af[i]  = *(const shortx8*)&sm.mm.As[(wm + i * 16 + fr) * 32 + fk_sw];
            bfr[i] = *(const shortx8*)&sm.mm.Bs[(wn + i * 16 + fr) * 32 + fk_sw];
        }
        #pragma unroll
        for (int i = 0; i < 4; ++i)
            #pragma unroll
            for (int j = 0; j < 4; ++j)
                acc[i][j] = __builtin_amdgcn_mfma_f32_16x16x32_bf16(
                    af[i], bfr[j], acc[i][j], 0, 0, 0);
        __syncthreads();
    }

    #pragma unroll
    for (int i = 0; i < 4; ++i) {
        const int r0 = wm + i * 16 + qd * 4;
        #pragma unroll
        for (int j = 0; j < 4; ++j) {
            const int c = wn + j * 16 + fr;
            union { unsigned short u[4]; uint2 v; } p;
            p.u[0] = f2bf(acc[i][j][0]);
            p.u[1] = f2bf(acc[i][j][1]);
            p.u[2] = f2bf(acc[i][j][2]);
            p.u[3] = f2bf(acc[i][j][3]);
            *(uint2*)&sm.Wt[c * 136 + r0] = p.v;
        }
    }
    __syncthreads();

    short* out = W + (size_t)go * IN_F + bn + h * 64;
    #pragma unroll
    for (int k = 0; k < 8; ++k) {
        const int qs[4] = { q4[k].x, q4[k].y, q4[k].z, q4[k].w };
        union { unsigned short u[8]; int4 v; } p;
        #pragma unroll
        for (int d = 0; d < 4; ++d) {
            const int q = qs[d];
            const int c = h * 64 + k * 8 + d * 2;
            const float l0 = bf2f((unsigned short)sm.Wt[c * 136 + r_o]);
            const float l1 = bf2f((unsigned short)sm.Wt[(c + 1) * 136 + r_o]);
            p.u[2 * d]     = f2bf(fmaf(nf4s[q & 15],        am, l0));
            p.u[2 * d + 1] = f2bf(fmaf(nf4s[(q >> 4) & 15], am, l1));
        }
        *(int4*)(out + k * 8) = p.v;
    }
}

// ---------------------------------------------------------------------------
// gemm_bt2: C[M][N] = Xb[M][K] * Wb[N][K]^T
// 256x256 tile, BK=64, 512 threads (8 waves: 2M x 4N, 128x64 C each).
// ROUND-4 CHANGE: TWO windows per K-tile (was 4), balanced reads 16/8:
//   W1: [rd A-lo(8)+B-all(8) | stage T+1.A1] -> lgkm -> 32 MFMA Q(0,*) -> SBAR
//   W2: [rd A-hi(8) | stage T+2.B0,B1,A0]   -> lgkm -> 32 MFMA Q(1,*)
//       -> vmcnt(6) -> SBAR
// bf regs stay live across the W1 barrier (reused by W2's quadrants).
// Longer windows + fewer sync points let wave-skew overlap the LDS-read
// pipe (~2300 cyc/K-tile) with the MFMA pipe (~2480 cyc/K-tile) instead of
// summing them (measured 4462 cyc/K-tile in round 3).
// Safety: per-wave lgkmcnt(0) precedes barrier arrival, so SBAR(W) ==> all
// reads of windows <= W serviced. Stage targets: T+1.A1 -> buf^1.A-hi,
// last read t-1.W2 (>=1 barrier); T+2.B -> cur.B, last read t.W1; T+2.A0 ->
// cur.A-lo, last read t.W1. vmcnt(6): 8 issues/tile, drain = exactly
// T(t+1); prologue leftover = T1.{A0,B0,B1} = 6 (unchanged from round 3).
// ---------------------------------------------------------------------------
#define BM2 256
#define BN2 256
#define BK2 64
#define NT2 (GK / BK2)   // 64

#define MFMA16(a, b, c) __builtin_amdgcn_mfma_f32_16x16x32_bf16((a), (b), (c), 0, 0, 0)
#define SBAR()  __builtin_amdgcn_s_barrier()
#define SFEN()  __builtin_amdgcn_sched_barrier(0)

__global__ __launch_bounds__(512, 2) void gemm_bt2(
    const short* __restrict__ Xb,   // M x K bf16
    const short* __restrict__ Wb,   // N x K bf16
    float*       __restrict__ C)    // M x N fp32
{
    // [buf:2][mat:2 (A,B)][half:2][row:128][k:64] bf16 = 128 KiB
    __shared__ short lds[2 * 32768];

    const int tid  = threadIdx.x;
    const int lane = tid & 63;
    const int wave = tid >> 6;
    const int bn = blockIdx.x * BN2;
    const int bm = blockIdx.y * BM2;

    const int wm = (wave >> 2) * 128;       // 0 or 128 (A half)
    const int wn = (wave & 3) * 64;         // 0,64,128,192
    const int fr = lane & 15;
    const int qd = lane >> 4;               // 0..3
    const int rsw = fr & 7;
    const int kof[2] = { ((0 * 4 + qd) ^ rsw) << 3, ((1 * 4 + qd) ^ rsw) << 3 };

    // staging: LDS dest linear in tid (gll16 requirement); global k-chunk
    // pre-swizzled: chunk = (tid&7) ^ (row&7).
    const int srow = tid >> 3;                       // 0..63
    const int gch  = (tid & 7) ^ (srow & 7);
    const short* pA = Xb + (size_t)(bm + srow) * GK + gch * 8;
    const short* pB = Wb + (size_t)(bn + srow) * GK + gch * 8;

    auto STAGE = [&](const short* P, int matOff, int h, int t, int buf) {
        short* d = lds + buf * 32768 + matOff + h * 8192 + tid * 8;
        const short* s = P + (size_t)(h * 128) * GK + (size_t)t * BK2;
        gll16(s, d);
        gll16(s + (size_t)64 * GK, d + 4096);
    };

    floatx4 zero = {0.f, 0.f, 0.f, 0.f};
    floatx4 acc[8][4];
    #pragma unroll
    for (int i = 0; i < 8; ++i)
        #pragma unroll
        for (int j = 0; j < 4; ++j) acc[i][j] = zero;

    // ---- prologue: T0 (4 half-tiles, buf0) + T1.{A0,B0,B1} (buf1) ----
    STAGE(pA, 0,     0, 0, 0);
    STAGE(pA, 0,     1, 0, 0);
    STAGE(pB, 16384, 0, 0, 0);
    STAGE(pB, 16384, 1, 0, 0);
    STAGE(pA, 0,     0, 1, 1);
    STAGE(pB, 16384, 0, 1, 1);
    STAGE(pB, 16384, 1, 1, 1);
    asm volatile("s_waitcnt vmcnt(6)" ::: "memory");   // T0 landed; T1 3 ht in flight
    SBAR();
    SFEN();

    for (int t = 0; t < NT2; ++t) {
        const int cur = t & 1;
        const short* Ah = lds + cur * 32768 + (wm >> 7) * 8192;
        const short* Bh = lds + cur * 32768 + 16384 + (wn >> 7) * 8192;
        const int bs = wn & 64;            // wave's strip base within B half

        shortx8 af[4][2], bf[4][2];

        // ---------------- W1: [rd A-lo(8) + B-all(8) | stage T(t+1).A1] ->
        //                  lgkm -> 32 MFMA Q(0,*) -> SBAR ----
        #pragma unroll
        for (int i = 0; i < 4; ++i) {
            af[i][0] = *(const shortx8*)(Ah + (i * 16 + fr) * 64 + kof[0]);
            af[i][1] = *(const shortx8*)(Ah + (i * 16 + fr) * 64 + kof[1]);
        }
        #pragma unroll
        for (int j = 0; j < 4; ++j) {
            bf[j][0] = *(const shortx8*)(Bh + (bs + j * 16 + fr) * 64 + kof[0]);
            bf[j][1] = *(const shortx8*)(Bh + (bs + j * 16 + fr) * 64 + kof[1]);
        }
        if (t + 1 < NT2) STAGE(pA, 0, 1, t + 1, cur ^ 1);
        SFEN();
        asm volatile("s_waitcnt lgkmcnt(0)" ::: "memory");
        SFEN();
        __builtin_amdgcn_s_setprio(1);
        #pragma unroll
        for (int i = 0; i < 4; ++i)
            #pragma unroll
            for (int j = 0; j < 4; ++j) {
                acc[i][j] = MFMA16(af[i][0], bf[j][0], acc[i][j]);
                acc[i][j] = MFMA16(af[i][1], bf[j][1], acc[i][j]);
            }
        __builtin_amdgcn_s_setprio(0);
        SFEN();
        SBAR();
        SFEN();

        // ---------------- W2: [rd A-hi(8) | stage T(t+2).B0,B1,A0] ->
        //                  lgkm -> 32 MFMA Q(1,*) -> vmcnt(6) -> SBAR ----
        #pragma unroll
        for (int i = 0; i < 4; ++i) {
            af[i][0] = *(const shortx8*)(Ah + (64 + i * 16 + fr) * 64 + kof[0]);
            af[i][1] = *(const shortx8*)(Ah + (64 + i * 16 + fr) * 64 + kof[1]);
        }
        if (t + 2 < NT2) {
            STAGE(pB, 16384, 0, t + 2, cur);
            STAGE(pB, 16384, 1, t + 2, cur);
            STAGE(pA, 0,     0, t + 2, cur);
        }
        SFEN();
        asm volatile("s_waitcnt lgkmcnt(0)" ::: "memory");
        SFEN();
        __builtin_amdgcn_s_setprio(1);
        #pragma unroll
        for (int i = 0; i < 4; ++i)
            #pragma unroll
            for (int j = 0; j < 4; ++j) {
                acc[4 + i][j] = MFMA16(af[i][0], bf[j][0], acc[4 + i][j]);
                acc[4 + i][j] = MFMA16(af[i][1], bf[j][1], acc[4 + i][j]);
            }
        __builtin_amdgcn_s_setprio(0);
        SFEN();
        if (t < NT2 - 2) {
            asm volatile("s_waitcnt vmcnt(6)" ::: "memory");   // T(t+1) landed
        } else if (t == NT2 - 2) {
            asm volatile("s_waitcnt vmcnt(0)" ::: "memory");   // last tile landed
        }
        SBAR();
        SFEN();
    }

    // epilogue: C/D layout col=lane&15, row=(lane>>4)*4+reg
    const int row0 = bm + wm + qd * 4;
    const int col0 = bn + wn + fr;
    #pragma unroll
    for (int i = 0; i < 8; ++i)
        #pragma unroll
        for (int j = 0; j < 4; ++j) {
            float* cp = C + (size_t)(row0 + i * 16) * OUT_F + col0 + j * 16;
            #pragma unroll
            for (int rr = 0; rr < 4; ++rr)
                cp[(size_t)rr * OUT_F] = acc[i][j][rr];
        }
}

// ---------------------------------------------------------------------------
extern "C" void kernel_launch(void* const* d_in, const int* in_sizes, int n_in,
                              void* d_out, int out_size, void* d_ws, size_t ws_size,
                              hipStream_t stream) {
    const float* x  = (const float*)d_in[0];
    const int*   qw = (const int*)d_in[1];
    const float* am = (const float*)d_in[2];
    const float* lA = (const float*)d_in[3];
    const float* lB = (const float*)d_in[4];
    float* out = (float*)d_out;

    short* Weff = (short*)d_ws;                                     // 32 MiB
    short* Xb   = (short*)((char*)d_ws + (size_t)OUT_F * IN_F * 2); // 64 MiB
    short* At   = (short*)((char*)d_ws + (size_t)(OUT_F * IN_F + M_ROWS * IN_F) * 2);
    short* Bb   = At + (size_t)IN_F * 64;   // At/Bb: 2 x 512 KiB past Xb

    prep<<<192, 256, 0, stream>>>(lA, lB, At, Bb);
    lora_weff<<<1024 + (M_ROWS * IN_F) / 2048, 256, 0, stream>>>(
        Bb, At, qw, am, Weff, x, Xb);
    gemm_bt2<<<dim3(OUT_F / BN2, M_ROWS / BM2), 512, 0, stream>>>(Xb, Weff, out);
}